// Round 5
// baseline (189.522 us; speedup 1.0000x reference)
//
#include <hip/hip_runtime.h>

#define BLOCK 256
#define MAX_BLOCKS 2048

typedef int int4v __attribute__((ext_vector_type(4)));

// ---------------------------------------------------------------- pack atoms
// coords (n,3) f32 + charges -> float4 {x,y,z,q}; sigma/eps -> float2 {s,e}
__global__ __launch_bounds__(BLOCK) void pack_atoms_kernel(
    const float* __restrict__ coords,
    const float* __restrict__ sigma,
    const float* __restrict__ eps,
    const float* __restrict__ charges,
    float4* __restrict__ xyzq,
    float2* __restrict__ se,
    int n)
{
    int a = blockIdx.x * blockDim.x + threadIdx.x;
    if (a < n) {
        float4 v;
        v.x = coords[3 * a + 0];
        v.y = coords[3 * a + 1];
        v.z = coords[3 * a + 2];
        v.w = charges[a];
        xyzq[a] = v;
        se[a] = make_float2(sigma[a], eps[a]);
    }
}

// ---------------------------------------------------------------- reduction
__device__ __forceinline__ void block_reduce_store(double acc, double* __restrict__ partials)
{
    for (int off = 32; off; off >>= 1) acc += __shfl_down(acc, off, 64);
    __shared__ double w[BLOCK / 64];
    int lane = threadIdx.x & 63;
    int wid  = threadIdx.x >> 6;
    if (lane == 0) w[wid] = acc;
    __syncthreads();
    if (threadIdx.x == 0) {
        double s = 0.0;
#pragma unroll
        for (int i = 0; i < BLOCK / 64; ++i) s += w[i];
        partials[blockIdx.x] = s;
    }
}

// ---------------------------------------------------------------- main (packed, fast path)
__global__ __launch_bounds__(BLOCK) void pair_energy_packed(
    const int4v* __restrict__ pairs4,   // 2 pairs per int4
    const float4* __restrict__ xyzq,
    const float2* __restrict__ se,
    const float* __restrict__ box,      // 9 floats, diagonal at 0,4,8
    const float* __restrict__ coulp,
    const float* __restrict__ cutp,
    double* __restrict__ partials,
    int n4)
{
    const float Lx = box[0], Ly = box[4], Lz = box[8];
    const float iLx = 1.0f / Lx, iLy = 1.0f / Ly, iLz = 1.0f / Lz;
    const float coul = coulp[0];
    const float cut  = cutp[0];
    const float cut2 = cut * cut;
    const float icut = 1.0f / cut;

    double acc = 0.0;
    const int stride = gridDim.x * blockDim.x;
    for (int idx = blockIdx.x * blockDim.x + threadIdx.x; idx < n4; idx += stride) {
        const int4v p = __builtin_nontemporal_load(&pairs4[idx]);  // streamed once
#pragma unroll
        for (int h = 0; h < 2; ++h) {
            const int ia = h ? p[2] : p[0];
            const int ja = h ? p[3] : p[1];
            const float4 A = xyzq[ia];
            const float4 B = xyzq[ja];
            float dx = A.x - B.x;
            float dy = A.y - B.y;
            float dz = A.z - B.z;
            dx -= rintf(dx * iLx) * Lx;   // round-half-even == jnp.round
            dy -= rintf(dy * iLy) * Ly;
            dz -= rintf(dz * iLz) * Lz;
            const float r2 = dx * dx + dy * dy + dz * dz;
            if (r2 < cut2) {              // ~0.54% of pairs pass
                const float inv_r = 1.0f / sqrtf(r2);
                float e = coul * A.w * B.w * (inv_r - icut);
                const float2 SA = se[ia];
                const float2 SB = se[ja];
                const float sg = 0.5f * (SA.x + SB.x) * inv_r;
                const float ep = sqrtf(SA.y * SB.y);
                const float s2 = sg * sg;
                const float s6 = s2 * s2 * s2;
                e += 4.0f * ep * (s6 * s6 - s6);
                acc += (double)e;
            }
        }
    }
    block_reduce_store(acc, partials);
}

// ---------------------------------------------------------------- main (direct gather, ws fallback)
__global__ __launch_bounds__(BLOCK) void pair_energy_direct(
    const int4v* __restrict__ pairs4,
    const float* __restrict__ coords,
    const float* __restrict__ sigma,
    const float* __restrict__ eps,
    const float* __restrict__ charges,
    const float* __restrict__ box,
    const float* __restrict__ coulp,
    const float* __restrict__ cutp,
    double* __restrict__ partials,
    int n4)
{
    const float Lx = box[0], Ly = box[4], Lz = box[8];
    const float iLx = 1.0f / Lx, iLy = 1.0f / Ly, iLz = 1.0f / Lz;
    const float coul = coulp[0];
    const float cut  = cutp[0];
    const float cut2 = cut * cut;
    const float icut = 1.0f / cut;

    double acc = 0.0;
    const int stride = gridDim.x * blockDim.x;
    for (int idx = blockIdx.x * blockDim.x + threadIdx.x; idx < n4; idx += stride) {
        const int4v p = __builtin_nontemporal_load(&pairs4[idx]);
#pragma unroll
        for (int h = 0; h < 2; ++h) {
            const int ia = h ? p[2] : p[0];
            const int ja = h ? p[3] : p[1];
            float dx = coords[3 * ia + 0] - coords[3 * ja + 0];
            float dy = coords[3 * ia + 1] - coords[3 * ja + 1];
            float dz = coords[3 * ia + 2] - coords[3 * ja + 2];
            dx -= rintf(dx * iLx) * Lx;
            dy -= rintf(dy * iLy) * Ly;
            dz -= rintf(dz * iLz) * Lz;
            const float r2 = dx * dx + dy * dy + dz * dz;
            if (r2 < cut2) {
                const float inv_r = 1.0f / sqrtf(r2);
                float e = coul * charges[ia] * charges[ja] * (inv_r - icut);
                const float sg = 0.5f * (sigma[ia] + sigma[ja]) * inv_r;
                const float ep = sqrtf(eps[ia] * eps[ja]);
                const float s2 = sg * sg;
                const float s6 = s2 * s2 * s2;
                e += 4.0f * ep * (s6 * s6 - s6);
                acc += (double)e;
            }
        }
    }
    block_reduce_store(acc, partials);
}

// ---------------------------------------------------------------- ultra fallback: float atomics to d_out
__global__ __launch_bounds__(BLOCK) void pair_energy_direct_f(
    const int4v* __restrict__ pairs4,
    const float* __restrict__ coords,
    const float* __restrict__ sigma,
    const float* __restrict__ eps,
    const float* __restrict__ charges,
    const float* __restrict__ box,
    const float* __restrict__ coulp,
    const float* __restrict__ cutp,
    float* __restrict__ out,
    int n4)
{
    const float Lx = box[0], Ly = box[4], Lz = box[8];
    const float iLx = 1.0f / Lx, iLy = 1.0f / Ly, iLz = 1.0f / Lz;
    const float coul = coulp[0];
    const float cut  = cutp[0];
    const float cut2 = cut * cut;
    const float icut = 1.0f / cut;

    double acc = 0.0;
    const int stride = gridDim.x * blockDim.x;
    for (int idx = blockIdx.x * blockDim.x + threadIdx.x; idx < n4; idx += stride) {
        const int4v p = __builtin_nontemporal_load(&pairs4[idx]);
#pragma unroll
        for (int h = 0; h < 2; ++h) {
            const int ia = h ? p[2] : p[0];
            const int ja = h ? p[3] : p[1];
            float dx = coords[3 * ia + 0] - coords[3 * ja + 0];
            float dy = coords[3 * ia + 1] - coords[3 * ja + 1];
            float dz = coords[3 * ia + 2] - coords[3 * ja + 2];
            dx -= rintf(dx * iLx) * Lx;
            dy -= rintf(dy * iLy) * Ly;
            dz -= rintf(dz * iLz) * Lz;
            const float r2 = dx * dx + dy * dy + dz * dz;
            if (r2 < cut2) {
                const float inv_r = 1.0f / sqrtf(r2);
                float e = coul * charges[ia] * charges[ja] * (inv_r - icut);
                const float sg = 0.5f * (sigma[ia] + sigma[ja]) * inv_r;
                const float ep = sqrtf(eps[ia] * eps[ja]);
                const float s2 = sg * sg;
                const float s6 = s2 * s2 * s2;
                e += 4.0f * ep * (s6 * s6 - s6);
                acc += (double)e;
            }
        }
    }
    for (int off = 32; off; off >>= 1) acc += __shfl_down(acc, off, 64);
    __shared__ double w[BLOCK / 64];
    int lane = threadIdx.x & 63;
    int wid  = threadIdx.x >> 6;
    if (lane == 0) w[wid] = acc;
    __syncthreads();
    if (threadIdx.x == 0) {
        double s = 0.0;
#pragma unroll
        for (int i = 0; i < BLOCK / 64; ++i) s += w[i];
        unsafeAtomicAdd(out, (float)s);
    }
}

// ---------------------------------------------------------------- finalize
__global__ __launch_bounds__(BLOCK) void reduce_partials(
    const double* __restrict__ partials, int n, float* __restrict__ out)
{
    double s = 0.0;
    for (int i = threadIdx.x; i < n; i += BLOCK) s += partials[i];
    for (int off = 32; off; off >>= 1) s += __shfl_down(s, off, 64);
    __shared__ double w[BLOCK / 64];
    int lane = threadIdx.x & 63;
    int wid  = threadIdx.x >> 6;
    if (lane == 0) w[wid] = s;
    __syncthreads();
    if (threadIdx.x == 0) {
        double t = 0.0;
#pragma unroll
        for (int i = 0; i < BLOCK / 64; ++i) t += w[i];
        out[0] = (float)t;
    }
}

// ---------------------------------------------------------------- launch
extern "C" void kernel_launch(void* const* d_in, const int* in_sizes, int n_in,
                              void* d_out, int out_size, void* d_ws, size_t ws_size,
                              hipStream_t stream)
{
    const float* coords  = (const float*)d_in[0];
    const int*   pairs   = (const int*)d_in[1];
    const float* box     = (const float*)d_in[2];
    const float* sigma   = (const float*)d_in[3];
    const float* eps     = (const float*)d_in[4];
    const float* charges = (const float*)d_in[5];
    const float* coulp   = (const float*)d_in[6];
    const float* cutp    = (const float*)d_in[7];
    float* out = (float*)d_out;

    const int n_atoms = in_sizes[3];          // sigma element count
    const int n_pairs = in_sizes[1] / 2;
    const int n4 = n_pairs / 2;               // int4 elements (2 pairs each); n_pairs is even

    int blocks = (n4 + BLOCK - 1) / BLOCK;
    if (blocks > MAX_BLOCKS) blocks = MAX_BLOCKS;

    const size_t xyzq_bytes = (size_t)n_atoms * sizeof(float4);
    const size_t se_bytes   = (size_t)n_atoms * sizeof(float2);
    const size_t part_bytes = (size_t)MAX_BLOCKS * sizeof(double);

    char* ws = (char*)d_ws;
    if (ws_size >= xyzq_bytes + se_bytes + part_bytes) {
        float4* xyzq     = (float4*)ws;
        float2* se       = (float2*)(ws + xyzq_bytes);
        double* partials = (double*)(ws + xyzq_bytes + se_bytes);
        pack_atoms_kernel<<<(n_atoms + BLOCK - 1) / BLOCK, BLOCK, 0, stream>>>(
            coords, sigma, eps, charges, xyzq, se, n_atoms);
        pair_energy_packed<<<blocks, BLOCK, 0, stream>>>(
            (const int4v*)pairs, xyzq, se, box, coulp, cutp, partials, n4);
        reduce_partials<<<1, BLOCK, 0, stream>>>(partials, blocks, out);
    } else if (ws_size >= part_bytes) {
        double* partials = (double*)ws;
        pair_energy_direct<<<blocks, BLOCK, 0, stream>>>(
            (const int4v*)pairs, coords, sigma, eps, charges, box, coulp, cutp, partials, n4);
        reduce_partials<<<1, BLOCK, 0, stream>>>(partials, blocks, out);
    } else {
        hipMemsetAsync(d_out, 0, sizeof(float), stream);
        pair_energy_direct_f<<<blocks, BLOCK, 0, stream>>>(
            (const int4v*)pairs, coords, sigma, eps, charges, box, coulp, cutp, out, n4);
    }
}

// Round 8
// 172.000 us; speedup vs baseline: 1.1019x; 1.1019x over previous
//
#include <hip/hip_runtime.h>

#define BLOCK 256
#define MAX_BLOCKS 2048

typedef int int4v __attribute__((ext_vector_type(4)));

// ---------------------------------------------------------------- pack atoms
// coords (n,3) f32 + charges -> float4 {x,y,z,q}; sigma/eps -> float2 {s,e}
__global__ __launch_bounds__(BLOCK) void pack_atoms_kernel(
    const float* __restrict__ coords,
    const float* __restrict__ sigma,
    const float* __restrict__ eps,
    const float* __restrict__ charges,
    float4* __restrict__ xyzq,
    float2* __restrict__ se,
    int n)
{
    int a = blockIdx.x * blockDim.x + threadIdx.x;
    if (a < n) {
        float4 v;
        v.x = coords[3 * a + 0];
        v.y = coords[3 * a + 1];
        v.z = coords[3 * a + 2];
        v.w = charges[a];
        xyzq[a] = v;
        se[a] = make_float2(sigma[a], eps[a]);
    }
}

// ---------------------------------------------------------------- reduction
__device__ __forceinline__ void block_reduce_store(double acc, double* __restrict__ partials)
{
    for (int off = 32; off; off >>= 1) acc += __shfl_down(acc, off, 64);
    __shared__ double w[BLOCK / 64];
    int lane = threadIdx.x & 63;
    int wid  = threadIdx.x >> 6;
    if (lane == 0) w[wid] = acc;
    __syncthreads();
    if (threadIdx.x == 0) {
        double s = 0.0;
#pragma unroll
        for (int i = 0; i < BLOCK / 64; ++i) s += w[i];
        partials[blockIdx.x] = s;
    }
}

// ---------------------------------------------------------------- per-pair energy
__device__ __forceinline__ double pair_e(
    const float4 A, const float4 B, int ia, int ja,
    const float2* __restrict__ se,
    float Lx, float Ly, float Lz, float iLx, float iLy, float iLz,
    float coul, float cut2, float icut)
{
    float dx = A.x - B.x;
    float dy = A.y - B.y;
    float dz = A.z - B.z;
    dx -= rintf(dx * iLx) * Lx;   // round-half-even == jnp.round
    dy -= rintf(dy * iLy) * Ly;
    dz -= rintf(dz * iLz) * Lz;
    const float r2 = dx * dx + dy * dy + dz * dz;
    if (r2 < cut2) {              // ~0.54% of pairs pass
        const float inv_r = 1.0f / sqrtf(r2);
        float e = coul * A.w * B.w * (inv_r - icut);
        const float2 SA = se[ia];
        const float2 SB = se[ja];
        const float sg = 0.5f * (SA.x + SB.x) * inv_r;
        const float ep = sqrtf(SA.y * SB.y);
        const float s2 = sg * sg;
        const float s6 = s2 * s2 * s2;
        e += 4.0f * ep * (s6 * s6 - s6);
        return (double)e;
    }
    return 0.0;
}

// ---------------------------------------------------------------- main (packed, 2x MLP)
__global__ __launch_bounds__(BLOCK) void pair_energy_packed(
    const int4v* __restrict__ pairs4,   // 2 pairs per int4
    const float4* __restrict__ xyzq,
    const float2* __restrict__ se,
    const float* __restrict__ box,      // 9 floats, diagonal at 0,4,8
    const float* __restrict__ coulp,
    const float* __restrict__ cutp,
    double* __restrict__ partials,
    int n4)
{
    const float Lx = box[0], Ly = box[4], Lz = box[8];
    const float iLx = 1.0f / Lx, iLy = 1.0f / Ly, iLz = 1.0f / Lz;
    const float coul = coulp[0];
    const float cut  = cutp[0];
    const float cut2 = cut * cut;
    const float icut = 1.0f / cut;

    const int half   = n4 >> 1;
    const int tid    = blockIdx.x * blockDim.x + threadIdx.x;
    const int stride = gridDim.x * blockDim.x;

    double acc = 0.0;
    // two coalesced streams -> 2 pairs-loads + 8 independent gathers in flight
    for (int idx = tid; idx < half; idx += stride) {
        const int4v p0 = pairs4[idx];
        const int4v p1 = pairs4[idx + half];
        const float4 A0 = xyzq[p0[0]];
        const float4 B0 = xyzq[p0[1]];
        const float4 A1 = xyzq[p0[2]];
        const float4 B1 = xyzq[p0[3]];
        const float4 A2 = xyzq[p1[0]];
        const float4 B2 = xyzq[p1[1]];
        const float4 A3 = xyzq[p1[2]];
        const float4 B3 = xyzq[p1[3]];
        acc += pair_e(A0, B0, p0[0], p0[1], se, Lx, Ly, Lz, iLx, iLy, iLz, coul, cut2, icut);
        acc += pair_e(A1, B1, p0[2], p0[3], se, Lx, Ly, Lz, iLx, iLy, iLz, coul, cut2, icut);
        acc += pair_e(A2, B2, p1[0], p1[1], se, Lx, Ly, Lz, iLx, iLy, iLz, coul, cut2, icut);
        acc += pair_e(A3, B3, p1[2], p1[3], se, Lx, Ly, Lz, iLx, iLy, iLz, coul, cut2, icut);
    }
    // odd-n4 tail (one int4 = 2 pairs), single thread
    if ((n4 & 1) && tid == 0) {
        const int4v p = pairs4[n4 - 1];
        const float4 A = xyzq[p[0]];
        const float4 B = xyzq[p[1]];
        const float4 C = xyzq[p[2]];
        const float4 D = xyzq[p[3]];
        acc += pair_e(A, B, p[0], p[1], se, Lx, Ly, Lz, iLx, iLy, iLz, coul, cut2, icut);
        acc += pair_e(C, D, p[2], p[3], se, Lx, Ly, Lz, iLx, iLy, iLz, coul, cut2, icut);
    }
    block_reduce_store(acc, partials);
}

// ---------------------------------------------------------------- main (direct gather, ws fallback)
__global__ __launch_bounds__(BLOCK) void pair_energy_direct(
    const int4v* __restrict__ pairs4,
    const float* __restrict__ coords,
    const float* __restrict__ sigma,
    const float* __restrict__ eps,
    const float* __restrict__ charges,
    const float* __restrict__ box,
    const float* __restrict__ coulp,
    const float* __restrict__ cutp,
    double* __restrict__ partials,
    int n4)
{
    const float Lx = box[0], Ly = box[4], Lz = box[8];
    const float iLx = 1.0f / Lx, iLy = 1.0f / Ly, iLz = 1.0f / Lz;
    const float coul = coulp[0];
    const float cut  = cutp[0];
    const float cut2 = cut * cut;
    const float icut = 1.0f / cut;

    double acc = 0.0;
    const int stride = gridDim.x * blockDim.x;
    for (int idx = blockIdx.x * blockDim.x + threadIdx.x; idx < n4; idx += stride) {
        const int4v p = pairs4[idx];
#pragma unroll
        for (int h = 0; h < 2; ++h) {
            const int ia = h ? p[2] : p[0];
            const int ja = h ? p[3] : p[1];
            float dx = coords[3 * ia + 0] - coords[3 * ja + 0];
            float dy = coords[3 * ia + 1] - coords[3 * ja + 1];
            float dz = coords[3 * ia + 2] - coords[3 * ja + 2];
            dx -= rintf(dx * iLx) * Lx;
            dy -= rintf(dy * iLy) * Ly;
            dz -= rintf(dz * iLz) * Lz;
            const float r2 = dx * dx + dy * dy + dz * dz;
            if (r2 < cut2) {
                const float inv_r = 1.0f / sqrtf(r2);
                float e = coul * charges[ia] * charges[ja] * (inv_r - icut);
                const float sg = 0.5f * (sigma[ia] + sigma[ja]) * inv_r;
                const float ep = sqrtf(eps[ia] * eps[ja]);
                const float s2 = sg * sg;
                const float s6 = s2 * s2 * s2;
                e += 4.0f * ep * (s6 * s6 - s6);
                acc += (double)e;
            }
        }
    }
    block_reduce_store(acc, partials);
}

// ---------------------------------------------------------------- ultra fallback: float atomics to d_out
__global__ __launch_bounds__(BLOCK) void pair_energy_direct_f(
    const int4v* __restrict__ pairs4,
    const float* __restrict__ coords,
    const float* __restrict__ sigma,
    const float* __restrict__ eps,
    const float* __restrict__ charges,
    const float* __restrict__ box,
    const float* __restrict__ coulp,
    const float* __restrict__ cutp,
    float* __restrict__ out,
    int n4)
{
    const float Lx = box[0], Ly = box[4], Lz = box[8];
    const float iLx = 1.0f / Lx, iLy = 1.0f / Ly, iLz = 1.0f / Lz;
    const float coul = coulp[0];
    const float cut  = cutp[0];
    const float cut2 = cut * cut;
    const float icut = 1.0f / cut;

    double acc = 0.0;
    const int stride = gridDim.x * blockDim.x;
    for (int idx = blockIdx.x * blockDim.x + threadIdx.x; idx < n4; idx += stride) {
        const int4v p = pairs4[idx];
#pragma unroll
        for (int h = 0; h < 2; ++h) {
            const int ia = h ? p[2] : p[0];
            const int ja = h ? p[3] : p[1];
            float dx = coords[3 * ia + 0] - coords[3 * ja + 0];
            float dy = coords[3 * ia + 1] - coords[3 * ja + 1];
            float dz = coords[3 * ia + 2] - coords[3 * ja + 2];
            dx -= rintf(dx * iLx) * Lx;
            dy -= rintf(dy * iLy) * Ly;
            dz -= rintf(dz * iLz) * Lz;
            const float r2 = dx * dx + dy * dy + dz * dz;
            if (r2 < cut2) {
                const float inv_r = 1.0f / sqrtf(r2);
                float e = coul * charges[ia] * charges[ja] * (inv_r - icut);
                const float sg = 0.5f * (sigma[ia] + sigma[ja]) * inv_r;
                const float ep = sqrtf(eps[ia] * eps[ja]);
                const float s2 = sg * sg;
                const float s6 = s2 * s2 * s2;
                e += 4.0f * ep * (s6 * s6 - s6);
                acc += (double)e;
            }
        }
    }
    for (int off = 32; off; off >>= 1) acc += __shfl_down(acc, off, 64);
    __shared__ double w[BLOCK / 64];
    int lane = threadIdx.x & 63;
    int wid  = threadIdx.x >> 6;
    if (lane == 0) w[wid] = acc;
    __syncthreads();
    if (threadIdx.x == 0) {
        double s = 0.0;
#pragma unroll
        for (int i = 0; i < BLOCK / 64; ++i) s += w[i];
        unsafeAtomicAdd(out, (float)s);
    }
}

// ---------------------------------------------------------------- finalize
__global__ __launch_bounds__(BLOCK) void reduce_partials(
    const double* __restrict__ partials, int n, float* __restrict__ out)
{
    double s = 0.0;
    for (int i = threadIdx.x; i < n; i += BLOCK) s += partials[i];
    for (int off = 32; off; off >>= 1) s += __shfl_down(s, off, 64);
    __shared__ double w[BLOCK / 64];
    int lane = threadIdx.x & 63;
    int wid  = threadIdx.x >> 6;
    if (lane == 0) w[wid] = s;
    __syncthreads();
    if (threadIdx.x == 0) {
        double t = 0.0;
#pragma unroll
        for (int i = 0; i < BLOCK / 64; ++i) t += w[i];
        out[0] = (float)t;
    }
}

// ---------------------------------------------------------------- launch
extern "C" void kernel_launch(void* const* d_in, const int* in_sizes, int n_in,
                              void* d_out, int out_size, void* d_ws, size_t ws_size,
                              hipStream_t stream)
{
    const float* coords  = (const float*)d_in[0];
    const int*   pairs   = (const int*)d_in[1];
    const float* box     = (const float*)d_in[2];
    const float* sigma   = (const float*)d_in[3];
    const float* eps     = (const float*)d_in[4];
    const float* charges = (const float*)d_in[5];
    const float* coulp   = (const float*)d_in[6];
    const float* cutp    = (const float*)d_in[7];
    float* out = (float*)d_out;

    const int n_atoms = in_sizes[3];          // sigma element count
    const int n_pairs = in_sizes[1] / 2;
    const int n4 = n_pairs / 2;               // int4 elements (2 pairs each); n_pairs is even

    // grid sized for the 2x-MLP loop (half-range per thread)
    int blocks = ((n4 / 2) + BLOCK - 1) / BLOCK;
    if (blocks > MAX_BLOCKS) blocks = MAX_BLOCKS;
    if (blocks < 1) blocks = 1;

    const size_t xyzq_bytes = (size_t)n_atoms * sizeof(float4);
    const size_t se_bytes   = (size_t)n_atoms * sizeof(float2);
    const size_t part_bytes = (size_t)MAX_BLOCKS * sizeof(double);

    char* ws = (char*)d_ws;
    if (ws_size >= xyzq_bytes + se_bytes + part_bytes) {
        float4* xyzq     = (float4*)ws;
        float2* se       = (float2*)(ws + xyzq_bytes);
        double* partials = (double*)(ws + xyzq_bytes + se_bytes);
        pack_atoms_kernel<<<(n_atoms + BLOCK - 1) / BLOCK, BLOCK, 0, stream>>>(
            coords, sigma, eps, charges, xyzq, se, n_atoms);
        pair_energy_packed<<<blocks, BLOCK, 0, stream>>>(
            (const int4v*)pairs, xyzq, se, box, coulp, cutp, partials, n4);
        reduce_partials<<<1, BLOCK, 0, stream>>>(partials, blocks, out);
    } else if (ws_size >= part_bytes) {
        double* partials = (double*)ws;
        pair_energy_direct<<<blocks, BLOCK, 0, stream>>>(
            (const int4v*)pairs, coords, sigma, eps, charges, box, coulp, cutp, partials, n4);
        reduce_partials<<<1, BLOCK, 0, stream>>>(partials, blocks, out);
    } else {
        hipMemsetAsync(d_out, 0, sizeof(float), stream);
        pair_energy_direct_f<<<blocks, BLOCK, 0, stream>>>(
            (const int4v*)pairs, coords, sigma, eps, charges, box, coulp, cutp, out, n4);
    }
}